// Round 5
// baseline (488.615 us; speedup 1.0000x reference)
//
#include <hip/hip_runtime.h>

// ---------------------------------------------------------------------------
// EncoderBlock on MI355X (gfx950).  B=2 T=2048 D=1024 H=16 KVH=4 HD=64
// DFF=4096 KW=15.  bf16 MFMA GEMMs (16x16x32), fp32 accumulate.
// R5: flash 8-wave/512-thread blocks (grid=256=1/CU, 16 waves/CU), 64KB LDS
// w/ row-XOR Ps swizzle; bf16 residual stream; vb buffer dropped.
// ---------------------------------------------------------------------------

#define TT   2048
#define NTOK 4096   // B*T

typedef __attribute__((ext_vector_type(8))) short short8;   // 8 x bf16
typedef __attribute__((ext_vector_type(4))) float floatx4;  // MFMA acc

__device__ __forceinline__ unsigned short f2bf(float f) {
  unsigned int u = __float_as_uint(f);
  u = (u + 0x7fffu + ((u >> 16) & 1u)) >> 16;   // RNE
  return (unsigned short)u;
}
__device__ __forceinline__ float bf2f(unsigned short s) {
  return __uint_as_float(((unsigned int)s) << 16);
}

// async global->LDS 16B DMA: LDS dst = wave-uniform base + lane*16
__device__ __forceinline__ void glds16(const void* g, void* lds_base) {
  __builtin_amdgcn_global_load_lds(
      (const __attribute__((address_space(1))) void*)g,
      (__attribute__((address_space(3))) void*)lds_base, 16, 0, 0);
}

// ---------------------------------------------------------------------------
// All 9 weight transposes fp32 [K][M] -> bf16 [M][K] in ONE launch.
// pm: 0 row=m | 1 pw_up pairing | 2 gate half | 3 up half   (see R4)
// ---------------------------------------------------------------------------
struct WJobs {
  const float* src[9];
  unsigned short* dst[9];
  int K[9], M[9], pm[9];
  int start[10];
};

__global__ __launch_bounds__(256) void wconv_all_kernel(WJobs tab) {
  int b = blockIdx.x;
  int j = 0;
  while (b >= tab.start[j + 1]) j++;
  int t = b - tab.start[j];
  const float* src = tab.src[j];
  unsigned short* dst = tab.dst[j];
  int K = tab.K[j], M = tab.M[j], pm = tab.pm[j];
  int mt = M >> 5;
  int m0 = (t % mt) * 32, k0 = (t / mt) * 32;
  int rowbase;
  if (pm == 0)      rowbase = m0;
  else if (pm == 1) rowbase = ((m0 & 1023) >> 5) * 64 + (m0 >> 10) * 32;
  else if (pm == 2) rowbase = (m0 >> 5) * 64;
  else              rowbase = (m0 >> 5) * 64 + 32;
  __shared__ float tile[32][33];
  int tx = threadIdx.x & 31, ty = threadIdx.x >> 5;  // 32 x 8
  for (int r = ty; r < 32; r += 8)
    tile[r][tx] = src[(size_t)(k0 + r) * M + m0 + tx];
  __syncthreads();
  for (int r = ty; r < 32; r += 8)
    dst[(size_t)(rowbase + r) * K + k0 + tx] = f2bf(tile[tx][r]);
}

// ---------------------------------------------------------------------------
// zcrms over D=1024: out_bf16 = (1+scale)*x/rms.  One block per token.
// ---------------------------------------------------------------------------
template <bool BF16IN>
__global__ __launch_bounds__(256) void rmsnorm_kernel(
    const void* __restrict__ xin, const float* __restrict__ scale,
    unsigned short* __restrict__ out) {
  int t = blockIdx.x, tid = threadIdx.x;
  float xv[4];
  if (BF16IN) {
    ushort4 u = ((const ushort4*)((const unsigned short*)xin + (size_t)t * 1024))[tid];
    xv[0] = bf2f(u.x); xv[1] = bf2f(u.y); xv[2] = bf2f(u.z); xv[3] = bf2f(u.w);
  } else {
    float4 u = ((const float4*)((const float*)xin + (size_t)t * 1024))[tid];
    xv[0] = u.x; xv[1] = u.y; xv[2] = u.z; xv[3] = u.w;
  }
  float ss = xv[0] * xv[0] + xv[1] * xv[1] + xv[2] * xv[2] + xv[3] * xv[3];
#pragma unroll
  for (int off = 32; off > 0; off >>= 1) ss += __shfl_down(ss, off);
  __shared__ float red[4];
  if ((tid & 63) == 0) red[tid >> 6] = ss;
  __syncthreads();
  float rinv = rsqrtf((red[0] + red[1] + red[2] + red[3]) * (1.0f / 1024.0f) + 1e-6f);
  float4 sv = ((const float4*)scale)[tid];
  ushort4 o;
  o.x = f2bf((1.0f + sv.x) * xv[0] * rinv);
  o.y = f2bf((1.0f + sv.y) * xv[1] * rinv);
  o.z = f2bf((1.0f + sv.z) * xv[2] * rinv);
  o.w = f2bf((1.0f + sv.w) * xv[3] * rinv);
  ((ushort4*)(out + (size_t)t * 1024))[tid] = o;
}

// ---------------------------------------------------------------------------
// GEMM  C[N][M] = A[N][K](bf16) * Bt[M][K](bf16)^T
// FUSE: 0 plain | 1 GLU a*sigmoid(b) | 2 relu(a)*relu(b)  (f-width = M/2)
// OUT:  0 f32 | 1 bf16.   RES: 0 none | 1 f32 resid | 2 bf16 resid.
// ---------------------------------------------------------------------------
template <int BN, int FUSE, int OUT, int RES>
__global__ __launch_bounds__(256, 2) void gemm_bt_kernel(
    const unsigned short* __restrict__ A, const unsigned short* __restrict__ Bt,
    void* __restrict__ Cout, const void* __restrict__ resid, int K, int M) {
  constexpr int NI = BN / 32;
  __shared__ __align__(16) unsigned short As[128 * 64];
  __shared__ __align__(16) unsigned short Bs[BN * 64];
  const int tid = threadIdx.x;
  const int wid = tid >> 6, lane = tid & 63;
  const int quad = lane >> 4, l16 = lane & 15;
  const int wm = (wid >> 1) * 64, wn = (wid & 1) * (BN / 2);
  const int row0 = blockIdx.y * 128;
  const int col0 = blockIdx.x * BN;

  floatx4 acc[4][NI];
#pragma unroll
  for (int mi = 0; mi < 4; mi++)
#pragma unroll
    for (int ni = 0; ni < NI; ni++) acc[mi][ni] = (floatx4){0.f, 0.f, 0.f, 0.f};

  const unsigned short* Ag = A + (size_t)row0 * K;
  const unsigned short* Bg = Bt + (size_t)col0 * K;

  for (int k0 = 0; k0 < K; k0 += 64) {
#pragma unroll
    for (int j = 0; j < 4; j++) {
      int ci = tid + j * 256;
      int r = ci >> 3, c = (ci & 7) ^ (r & 7);
      glds16(Ag + (size_t)r * K + k0 + c * 8, &As[(wid * 64 + j * 256) * 8]);
    }
#pragma unroll
    for (int j = 0; j < BN / 32; j++) {
      int ci = tid + j * 256;
      int r = ci >> 3, c = (ci & 7) ^ (r & 7);
      glds16(Bg + (size_t)r * K + k0 + c * 8, &Bs[(wid * 64 + j * 256) * 8]);
    }
    __syncthreads();
#pragma unroll
    for (int kk = 0; kk < 64; kk += 32) {
      short8 a[4], b[NI];
#pragma unroll
      for (int mi = 0; mi < 4; mi++) {
        int r = wm + mi * 16 + l16;
        a[mi] = *(const short8*)&As[r * 64 + (((kk >> 3) + quad) ^ (r & 7)) * 8];
      }
#pragma unroll
      for (int ni = 0; ni < NI; ni++) {
        int r = wn + ni * 16 + l16;
        b[ni] = *(const short8*)&Bs[r * 64 + (((kk >> 3) + quad) ^ (r & 7)) * 8];
      }
#pragma unroll
      for (int mi = 0; mi < 4; mi++)
#pragma unroll
        for (int ni = 0; ni < NI; ni++)
          acc[mi][ni] = __builtin_amdgcn_mfma_f32_16x16x32_bf16(a[mi], b[ni], acc[mi][ni], 0, 0, 0);
    }
    __syncthreads();
  }

  if (FUSE == 0) {
#pragma unroll
    for (int mi = 0; mi < 4; mi++) {
#pragma unroll
      for (int reg = 0; reg < 4; reg++) {
        int grow = row0 + wm + mi * 16 + quad * 4 + reg;
#pragma unroll
        for (int ni = 0; ni < NI; ni++) {
          int gcol = col0 + wn + ni * 16 + l16;
          float v = acc[mi][ni][reg];
          if (RES == 1) v += ((const float*)resid)[(size_t)grow * M + gcol];
          if (RES == 2) v += bf2f(((const unsigned short*)resid)[(size_t)grow * M + gcol]);
          if (OUT == 1) ((unsigned short*)Cout)[(size_t)grow * M + gcol] = f2bf(v);
          else          ((float*)Cout)[(size_t)grow * M + gcol] = v;
        }
      }
    }
  } else {
    const int group = (col0 + wn) >> 6;
    const int MW = M >> 1;
#pragma unroll
    for (int mi = 0; mi < 4; mi++) {
#pragma unroll
      for (int reg = 0; reg < 4; reg++) {
        int grow = row0 + wm + mi * 16 + quad * 4 + reg;
#pragma unroll
        for (int ni = 0; ni < NI / 2; ni++) {
          int f = group * 32 + ni * 16 + l16;
          float a = acc[mi][ni][reg], b = acc[mi][ni + NI / 2][reg];
          float v;
          if (FUSE == 1) v = a / (1.0f + __expf(-b));
          else           v = fmaxf(a, 0.f) * fmaxf(b, 0.f);
          ((unsigned short*)Cout)[(size_t)grow * MW + f] = f2bf(v);
        }
      }
    }
  }
}

// ---------------------------------------------------------------------------
// Per-head zcrms (HD=64) + RoPE for q,k (bf16 in).
// q gets *QSCALE = log2(e)/8 folded in (flash uses exp2).
// ---------------------------------------------------------------------------
#define QSCALE 0.180336880111f   // log2(e)/8

__global__ __launch_bounds__(256) void qknorm_rope_kernel(
    const unsigned short* __restrict__ qkv, const float* __restrict__ cosb,
    const float* __restrict__ sinb, const float* __restrict__ qns,
    const float* __restrict__ kns, unsigned short* __restrict__ qb,
    unsigned short* __restrict__ kb) {
  int tok = blockIdx.x;
  int tid = threadIdx.x, w = tid >> 6, lane = tid & 63;
  int pos = tok & (TT - 1);
  int half = lane & 31;
  float c = cosb[pos * 32 + half], s = sinb[pos * 32 + half];
  const unsigned short* row = qkv + (size_t)tok * 1536;
  for (int hr = w; hr < 20; hr += 4) {   // 16 q-heads + 4 k-heads
    float v = bf2f(row[hr * 64 + lane]);
    float ss = v * v;
#pragma unroll
    for (int off = 32; off > 0; off >>= 1) ss += __shfl_xor(ss, off);
    float rinv = rsqrtf(ss * (1.0f / 64.0f) + 1e-6f);
    float sc = (hr < 16) ? qns[lane] : kns[lane];
    float nv = (1.0f + sc) * v * rinv;
    float partner = __shfl_xor(nv, 32);
    float outv = (lane < 32) ? (nv * c - partner * s) : (nv * c + partner * s);
    if (hr < 16) qb[(size_t)tok * 1024 + hr * 64 + lane] = f2bf(outv * QSCALE);
    else         kb[(size_t)tok * 256 + (hr - 16) * 64 + lane] = f2bf(outv);
  }
}

// ---------------------------------------------------------------------------
// V transpose straight from qkv GEMM output (bf16, offset 1280 in 1536 row):
// -> vt [(bi*4+kvh)*64+d][2048 keys]
// ---------------------------------------------------------------------------
__global__ __launch_bounds__(256) void vtrans_kernel(
    const unsigned short* __restrict__ qkv, unsigned short* __restrict__ vt) {
  __shared__ unsigned short t[64 * 65];
  int ktile = blockIdx.x;            // 0..31
  int g = blockIdx.y;                // bi*4+kvh, 0..7
  int bi = g >> 2, kvh = g & 3;
  int tid = threadIdx.x;
#pragma unroll
  for (int j = 0; j < 2; j++) {
    int ci = tid + j * 256;
    int r = ci >> 3, c8 = (ci & 7) * 8;
    union { uint4 v; unsigned short u[8]; } uu;
    uu.v = *(const uint4*)(qkv + (size_t)(bi * TT + ktile * 64 + r) * 1536 +
                           1280 + kvh * 64 + c8);
#pragma unroll
    for (int e = 0; e < 8; e++) t[r * 65 + c8 + e] = uu.u[e];
  }
  __syncthreads();
#pragma unroll
  for (int j = 0; j < 2; j++) {
    int ci = tid + j * 256;
    int d = ci >> 3, c8 = (ci & 7) * 8;
    union { uint4 v; unsigned short u[8]; } uu;
#pragma unroll
    for (int e = 0; e < 8; e++) uu.u[e] = t[(c8 + e) * 65 + d];
    *(uint4*)(vt + ((size_t)(g * 64 + d)) * TT + ktile * 64 + c8) = uu.v;
  }
}

// ---------------------------------------------------------------------------
// Flash attention (mask all-True, logits bounded -> no max-subtraction).
// 256 q-rows/block, 8 waves x 32 q-rows, 512 threads, grid 8x32 = 256 blocks
// (1/CU, 16 waves/CU).  Q in regs; K,V^T staged via glds16 (XOR swizzle);
// one barrier/iter (double buffer).  Ps: unpadded stride-64 with row-XOR
// chunk swizzle (2-way banks on both sides).  Rowsum via MFMA with ones.
// Total LDS = 16K + 16K + 32K = 64 KB.
// ---------------------------------------------------------------------------
__global__ __launch_bounds__(512) void flash_kernel(
    const unsigned short* __restrict__ qb, const unsigned short* __restrict__ kb,
    const unsigned short* __restrict__ vt, unsigned short* __restrict__ ob) {
  const int qt = blockIdx.x;          // 0..7 (256 q rows)
  const int bh = blockIdx.y;          // 0..31
  const int bi = bh >> 4, h = bh & 15, kvh = h >> 2;
  const int tid = threadIdx.x, w = tid >> 6, lane = tid & 63;
  const int quad = lane >> 4, l16 = lane & 15;

  __shared__ __align__(16) unsigned short Ks[2][64 * 64];
  __shared__ __align__(16) unsigned short Vs[2][64 * 64];
  __shared__ __align__(16) unsigned short Ps[256 * 64];

  const unsigned short* qsrc = qb + ((size_t)(bi * TT + qt * 256)) * 1024 + h * 64;
  short8 qf[2][2];
#pragma unroll
  for (int af = 0; af < 2; af++) {
    const unsigned short* qr = qsrc + (size_t)(w * 32 + af * 16 + l16) * 1024;
    qf[af][0] = *(const short8*)(qr + quad * 8);
    qf[af][1] = *(const short8*)(qr + 32 + quad * 8);
  }

  const unsigned short* kbase = kb + ((size_t)(bi * TT)) * 256 + kvh * 64;
  const unsigned short* vbase = vt + ((size_t)(bi * 4 + kvh)) * (64 * TT);

  floatx4 oacc[2][4];
  floatx4 lacc[2];
#pragma unroll
  for (int af = 0; af < 2; af++) {
    lacc[af] = (floatx4){0.f, 0.f, 0.f, 0.f};
#pragma unroll
    for (int di = 0; di < 4; di++) oacc[af][di] = (floatx4){0.f, 0.f, 0.f, 0.f};
  }
  const short8 ones = (short8){0x3F80, 0x3F80, 0x3F80, 0x3F80,
                               0x3F80, 0x3F80, 0x3F80, 0x3F80};

  {  // prologue: stage kt=0 (512 chunks per tile, 1 per thread)
    int r = tid >> 3, c = (tid & 7) ^ (r & 7);
    glds16(kbase + (size_t)r * 256 + c * 8, &Ks[0][w * 512]);
    glds16(vbase + (size_t)r * TT + c * 8, &Vs[0][w * 512]);
  }

  for (int kt = 0; kt < 32; kt++) {
    const int buf = kt & 1;
    __syncthreads();
    if (kt < 31) {
      int r = tid >> 3, c = (tid & 7) ^ (r & 7);
      glds16(kbase + (size_t)((kt + 1) * 64 + r) * 256 + c * 8, &Ks[buf ^ 1][w * 512]);
      glds16(vbase + (size_t)r * TT + (kt + 1) * 64 + c * 8, &Vs[buf ^ 1][w * 512]);
    }

    short8 kf[4][2];
#pragma unroll
    for (int ni = 0; ni < 4; ni++) {
      int rb = ni * 16 + l16;
      kf[ni][0] = *(const short8*)&Ks[buf][rb * 64 + ((quad ^ (rb & 7)) * 8)];
      kf[ni][1] = *(const short8*)&Ks[buf][rb * 64 + (((4 + quad) ^ (rb & 7)) * 8)];
    }
#pragma unroll
    for (int af = 0; af < 2; af++) {
#pragma unroll
      for (int ni = 0; ni < 4; ni++) {
        floatx4 s = (floatx4){0.f, 0.f, 0.f, 0.f};
        s = __builtin_amdgcn_mfma_f32_16x16x32_bf16(qf[af][0], kf[ni][0], s, 0, 0, 0);
        s = __builtin_amdgcn_mfma_f32_16x16x32_bf16(qf[af][1], kf[ni][1], s, 0, 0, 0);
        // write P[rr][col = ni*16+l16], chunk-XOR by row: chunk = (col>>3)^(rr&7)
#pragma unroll
        for (int r = 0; r < 4; r++) {
          int rr = w * 32 + af * 16 + quad * 4 + r;
          int ch = (ni * 2 + (l16 >> 3)) ^ (rr & 7);
          Ps[rr * 64 + ch * 8 + (l16 & 7)] =
              (unsigned short)(__float_as_uint(__builtin_amdgcn_exp2f(s[r])) >> 16);
        }
      }
    }
    short8 vf[4][2];
#pragma unroll
    for (int di = 0; di < 4; di++) {
      int rb = di * 16 + l16;
      vf[di][0] = *(const short8*)&Vs[buf][rb * 64 + ((quad ^ (rb & 7)) * 8)];
      vf[di][1] = *(const short8*)&Vs[buf][rb * 64 + (((4 + quad) ^ (rb & 7)) * 8)];
    }
#pragma unroll
    for (int af = 0; af < 2; af++) {
      const int rr = w * 32 + af * 16 + l16;   // rr&7 == l16&7
      short8 pa0 = *(const short8*)&Ps[rr * 64 + ((quad ^ (rr & 7)) * 8)];
      short8 pa1 = *(const short8*)&Ps[rr * 64 + (((4 + quad) ^ (rr & 7)) * 8)];
      lacc[af] = __builtin_amdgcn_mfma_f32_16x16x32_bf16(pa0, ones, lacc[af], 0, 0, 0);
      lacc[af] = __builtin_amdgcn_mfma_f32_16x16x32_bf16(pa1, ones, lacc[af], 0, 0, 0);
#pragma unroll
      for (int di = 0; di < 4; di++) {
        oacc[af][di] = __builtin_amdgcn_mfma_f32_16x16x32_bf16(pa0, vf[di][0], oacc[af][di], 0, 0, 0);
        oacc[af][di] = __builtin_amdgcn_mfma_f32_16x16x32_bf16(pa1, vf[di][1], oacc[af][di], 0, 0, 0);
      }
    }
  }

  unsigned short* obase = ob + ((size_t)(bi * TT + qt * 256)) * 1024 + h * 64;
#pragma unroll
  for (int af = 0; af < 2; af++) {
    float rl[4];
#pragma unroll
    for (int r = 0; r < 4; r++) rl[r] = 1.0f / lacc[af][r];
#pragma unroll
    for (int di = 0; di < 4; di++)
#pragma unroll
      for (int r = 0; r < 4; r++) {
        int qrow = w * 32 + af * 16 + quad * 4 + r;
        obase[(size_t)qrow * 1024 + di * 16 + l16] = f2bf(oacc[af][di][r] * rl[r]);
      }
  }
}

// ---------------------------------------------------------------------------
// Depthwise conv (KW=15, SAME, per-batch time axis) + zcrms.  Block per token.
// ---------------------------------------------------------------------------
__global__ __launch_bounds__(256) void convnorm_kernel(
    const unsigned short* __restrict__ g, const float* __restrict__ dw,
    const float* __restrict__ scale, unsigned short* __restrict__ out) {
  int tok = blockIdx.x;
  int bi = tok >> 11, pos = tok & (TT - 1);
  int tid = threadIdx.x, c0 = tid * 4;
  float a0 = 0.f, a1 = 0.f, a2 = 0.f, a3 = 0.f;
#pragma unroll
  for (int wk = 0; wk < 15; wk++) {
    int pp = pos + wk - 7;
    if (pp < 0 || pp >= TT) continue;
    ushort4 gv = *(const ushort4*)(g + ((size_t)(bi * TT + pp)) * 1024 + c0);
    float4 kv = *(const float4*)(dw + wk * 1024 + c0);
    a0 += bf2f(gv.x) * kv.x;
    a1 += bf2f(gv.y) * kv.y;
    a2 += bf2f(gv.z) * kv.z;
    a3 += bf2f(gv.w) * kv.w;
  }
  float ss = a0 * a0 + a1 * a1 + a2 * a2 + a3 * a3;
#pragma unroll
  for (int off = 32; off > 0; off >>= 1) ss += __shfl_down(ss, off);
  __shared__ float red[4];
  if ((tid & 63) == 0) red[tid >> 6] = ss;
  __syncthreads();
  float rinv = rsqrtf((red[0] + red[1] + red[2] + red[3]) * (1.0f / 1024.0f) + 1e-6f);
  float4 sv = *(const float4*)(scale + c0);
  ushort4 o;
  o.x = f2bf((1.0f + sv.x) * a0 * rinv);
  o.y = f2bf((1.0f + sv.y) * a1 * rinv);
  o.z = f2bf((1.0f + sv.z) * a2 * rinv);
  o.w = f2bf((1.0f + sv.w) * a3 * rinv);
  *(ushort4*)(out + (size_t)tok * 1024 + c0) = o;
}

// ---------------------------------------------------------------------------
extern "C" void kernel_launch(void* const* d_in, const int* in_sizes, int n_in,
                              void* d_out, int out_size, void* d_ws, size_t ws_size,
                              hipStream_t stream) {
  const float* x        = (const float*)d_in[0];
  const float* cosb     = (const float*)d_in[2];
  const float* sinb     = (const float*)d_in[3];
  const float* attn_ns  = (const float*)d_in[4];
  const float* qkern    = (const float*)d_in[5];
  const float* kkern    = (const float*)d_in[6];
  const float* vkern    = (const float*)d_in[7];
  const float* qns      = (const float*)d_in[8];
  const float* kns      = (const float*)d_in[9];
  const float* okern    = (const float*)d_in[10];
  const float* conv_ns  = (const float*)d_in[11];
  const float* pwupk    = (const float*)d_in[12];
  const float* dwk      = (const float*)d_in[13];
  const float* convi_ns = (const float*)d_in[14];
  const float* pwdnk    = (const float*)d_in[15];
  const float* ffn_ns   = (const float*)d_in[16];
  const float* gatek    = (const float*)d_in[17];
  const float* upk      = (const float*)d_in[18];
  const float* downk    = (const float*)d_in[19];
  float* out = (float*)d_out;
  char* ws = (char*)d_ws;

  const size_t O_QKVT = 0;
  const size_t O_OT   = O_QKVT + (size_t)1536 * 1024 * 2;
  const size_t O_UPT  = O_OT   + (size_t)1024 * 1024 * 2;
  const size_t O_DNT  = O_UPT  + (size_t)2048 * 1024 * 2;
  const size_t O_GUT  = O_DNT  + (size_t)1024 * 1024 * 2;
  const size_t O_DWNT = O_GUT  + (size_t)8192 * 1024 * 2;
  const size_t O_H    = O_DWNT + (size_t)4096 * 1024 * 2;
  const size_t O_BIG1 = O_H    + (size_t)4096 * 1024 * 2;   // qkv bf16 / ff bf16
  const size_t O_QB   = O_BIG1 + (size_t)4096 * 8192 * 2;
  const size_t O_KB   = O_QB   + (size_t)4096 * 1024 * 2;
  const size_t O_VT   = O_KB   + (size_t)4096 * 256 * 2;
  const size_t O_ECN  = O_VT   + (size_t)8 * 64 * 2048 * 2; // attn bf16 / cn bf16
  const size_t O_X1   = O_ECN  + (size_t)4096 * 1024 * 2;   // bf16
  const size_t O_X2   = O_X1   + (size_t)4096 * 1024 * 2;   // bf16
  const size_t O_BIG2 = O_X2   + (size_t)4096 * 1024 * 2;   // g bf16

  unsigned short* qkvT = (unsigned short*)(ws + O_QKVT);
  unsigned short* oT   = (unsigned short*)(ws + O_OT);
  unsigned short* upT  = (unsigned short*)(ws + O_UPT);
  unsigned short* dnT  = (unsigned short*)(ws + O_DNT);
  unsigned short* guT  = (unsigned short*)(ws + O_GUT);
  unsigned short* dwT  = (unsigned short*)(ws + O_DWNT);
  unsigned short* hbuf = (unsigned short*)(ws + O_H);
  unsigned short* big1u = (unsigned short*)(ws + O_BIG1);
  unsigned short* qbuf = (unsigned short*)(ws + O_QB);
  unsigned short* kbuf = (unsigned short*)(ws + O_KB);
  unsigned short* vtb  = (unsigned short*)(ws + O_VT);
  unsigned short* ecn  = (unsigned short*)(ws + O_ECN);
  unsigned short* x1b  = (unsigned short*)(ws + O_X1);
  unsigned short* x2b  = (unsigned short*)(ws + O_X2);
  unsigned short* big2 = (unsigned short*)(ws + O_BIG2);

  WJobs tab;
  tab.src[0] = qkern;  tab.dst[0] = qkvT;                       tab.K[0] = 1024; tab.M[0] = 1024; tab.pm[0] = 0;
  tab.src[1] = kkern;  tab.dst[1] = qkvT + (size_t)1024 * 1024; tab.K[1] = 1024; tab.M[1] = 256;  tab.pm[1] = 0;
  tab.src[2] = vkern;  tab.dst[2] = qkvT + (size_t)1280 * 1024; tab.K[2] = 1024; tab.M[2] = 256;  tab.pm[2] = 0;
  tab.src[3] = okern;  tab.dst[3] = oT;                         tab.K[3] = 1024; tab.M[3] = 1024; tab.pm[3] = 0;
  tab.src[4] = pwupk;  tab.dst[4] = upT;                        tab.K[4] = 1024; tab.M[4] = 2048; tab.pm[4] = 1;
  tab.src[5] = pwdnk;  tab.dst[5] = dnT;                        tab.K[5] = 1024; tab.M[5] = 1024; tab.pm[5] = 0;
  tab.src[6] = gatek;  tab.dst[6] = guT;                        tab.K[6] = 1024; tab.M[6] = 4096; tab.pm[6] = 2;
  tab.src[7] = upk;    tab.dst[7] = guT;                        tab.K[7] = 1024; tab.M[7] = 4096; tab.pm[7] = 3;
  tab.src[8] = downk;  tab.dst[8] = dwT;                        tab.K[8] = 4096; tab.M[8] = 1024; tab.pm[8] = 0;
  tab.start[0] = 0;
  for (int i = 0; i < 9; i++)
    tab.start[i + 1] = tab.start[i] + (tab.M[i] >> 5) * (tab.K[i] >> 5);
  wconv_all_kernel<<<tab.start[9], 256, 0, stream>>>(tab);

  // attention block
  rmsnorm_kernel<false><<<NTOK, 256, 0, stream>>>(x, attn_ns, hbuf);
  gemm_bt_kernel<128, 0, 1, 0><<<dim3(12, 32), 256, 0, stream>>>(
      hbuf, qkvT, big1u, nullptr, 1024, 1536);
  qknorm_rope_kernel<<<NTOK, 256, 0, stream>>>(big1u, cosb, sinb, qns, kns,
                                               qbuf, kbuf);
  vtrans_kernel<<<dim3(32, 8), 256, 0, stream>>>(big1u, vtb);
  flash_kernel<<<dim3(8, 32), 512, 0, stream>>>(qbuf, kbuf, vtb, ecn);
  gemm_bt_kernel<64, 0, 1, 1><<<dim3(16, 32), 256, 0, stream>>>(
      ecn, oT, x1b, x, 1024, 1024);

  // conv block
  rmsnorm_kernel<true><<<NTOK, 256, 0, stream>>>(x1b, conv_ns, hbuf);
  gemm_bt_kernel<128, 1, 1, 0><<<dim3(16, 32), 256, 0, stream>>>(
      hbuf, upT, big2, nullptr, 1024, 2048);      // fused GLU -> g [NTOK][1024]
  convnorm_kernel<<<NTOK, 256, 0, stream>>>(big2, dwk, convi_ns, ecn);
  gemm_bt_kernel<64, 0, 1, 2><<<dim3(16, 32), 256, 0, stream>>>(
      ecn, dnT, x2b, x1b, 1024, 1024);

  // ffn block
  rmsnorm_kernel<true><<<NTOK, 256, 0, stream>>>(x2b, ffn_ns, hbuf);
  gemm_bt_kernel<128, 2, 1, 0><<<dim3(64, 32), 256, 0, stream>>>(
      hbuf, guT, big1u, nullptr, 1024, 8192);     // fused relu*relu -> ff
  gemm_bt_kernel<64, 0, 0, 2><<<dim3(16, 32), 256, 0, stream>>>(
      big1u, dwT, out, x2b, 4096, 1024);
}

// Round 6
// 484.757 us; speedup vs baseline: 1.0080x; 1.0080x over previous
//
#include <hip/hip_runtime.h>

// ---------------------------------------------------------------------------
// EncoderBlock on MI355X (gfx950).  B=2 T=2048 D=1024 H=16 KVH=4 HD=64
// DFF=4096 KW=15.  bf16 MFMA GEMMs (16x16x32), fp32 accumulate.
// R6: flash computes S^T (operand swap) -> packed ds_write_b64 P-writes;
// 8x8 block-patch swizzle on GEMMs for L2 locality; named GEMM wrappers.
// ---------------------------------------------------------------------------

#define TT   2048
#define NTOK 4096   // B*T

typedef __attribute__((ext_vector_type(8))) short short8;   // 8 x bf16
typedef __attribute__((ext_vector_type(4))) float floatx4;  // MFMA acc

__device__ __forceinline__ unsigned short f2bf(float f) {
  unsigned int u = __float_as_uint(f);
  u = (u + 0x7fffu + ((u >> 16) & 1u)) >> 16;   // RNE
  return (unsigned short)u;
}
__device__ __forceinline__ float bf2f(unsigned short s) {
  return __uint_as_float(((unsigned int)s) << 16);
}

// async global->LDS 16B DMA: LDS dst = wave-uniform base + lane*16
__device__ __forceinline__ void glds16(const void* g, void* lds_base) {
  __builtin_amdgcn_global_load_lds(
      (const __attribute__((address_space(1))) void*)g,
      (__attribute__((address_space(3))) void*)lds_base, 16, 0, 0);
}

// ---------------------------------------------------------------------------
// All 9 weight transposes fp32 [K][M] -> bf16 [M][K] in ONE launch.
// pm: 0 row=m | 1 pw_up pairing | 2 gate half | 3 up half
// ---------------------------------------------------------------------------
struct WJobs {
  const float* src[9];
  unsigned short* dst[9];
  int K[9], M[9], pm[9];
  int start[10];
};

__global__ __launch_bounds__(256) void wconv_all_kernel(WJobs tab) {
  int b = blockIdx.x;
  int j = 0;
  while (b >= tab.start[j + 1]) j++;
  int t = b - tab.start[j];
  const float* src = tab.src[j];
  unsigned short* dst = tab.dst[j];
  int K = tab.K[j], M = tab.M[j], pm = tab.pm[j];
  int mt = M >> 5;
  int m0 = (t % mt) * 32, k0 = (t / mt) * 32;
  int rowbase;
  if (pm == 0)      rowbase = m0;
  else if (pm == 1) rowbase = ((m0 & 1023) >> 5) * 64 + (m0 >> 10) * 32;
  else if (pm == 2) rowbase = (m0 >> 5) * 64;
  else              rowbase = (m0 >> 5) * 64 + 32;
  __shared__ float tile[32][33];
  int tx = threadIdx.x & 31, ty = threadIdx.x >> 5;  // 32 x 8
  for (int r = ty; r < 32; r += 8)
    tile[r][tx] = src[(size_t)(k0 + r) * M + m0 + tx];
  __syncthreads();
  for (int r = ty; r < 32; r += 8)
    dst[(size_t)(rowbase + r) * K + k0 + tx] = f2bf(tile[tx][r]);
}

// ---------------------------------------------------------------------------
// zcrms over D=1024: out_bf16 = (1+scale)*x/rms.  One block per token.
// ---------------------------------------------------------------------------
template <bool BF16IN>
__global__ __launch_bounds__(256) void rmsnorm_kernel(
    const void* __restrict__ xin, const float* __restrict__ scale,
    unsigned short* __restrict__ out) {
  int t = blockIdx.x, tid = threadIdx.x;
  float xv[4];
  if (BF16IN) {
    ushort4 u = ((const ushort4*)((const unsigned short*)xin + (size_t)t * 1024))[tid];
    xv[0] = bf2f(u.x); xv[1] = bf2f(u.y); xv[2] = bf2f(u.z); xv[3] = bf2f(u.w);
  } else {
    float4 u = ((const float4*)((const float*)xin + (size_t)t * 1024))[tid];
    xv[0] = u.x; xv[1] = u.y; xv[2] = u.z; xv[3] = u.w;
  }
  float ss = xv[0] * xv[0] + xv[1] * xv[1] + xv[2] * xv[2] + xv[3] * xv[3];
#pragma unroll
  for (int off = 32; off > 0; off >>= 1) ss += __shfl_down(ss, off);
  __shared__ float red[4];
  if ((tid & 63) == 0) red[tid >> 6] = ss;
  __syncthreads();
  float rinv = rsqrtf((red[0] + red[1] + red[2] + red[3]) * (1.0f / 1024.0f) + 1e-6f);
  float4 sv = ((const float4*)scale)[tid];
  ushort4 o;
  o.x = f2bf((1.0f + sv.x) * xv[0] * rinv);
  o.y = f2bf((1.0f + sv.y) * xv[1] * rinv);
  o.z = f2bf((1.0f + sv.z) * xv[2] * rinv);
  o.w = f2bf((1.0f + sv.w) * xv[3] * rinv);
  ((ushort4*)(out + (size_t)t * 1024))[tid] = o;
}

// ---------------------------------------------------------------------------
// GEMM body.  C[N][M] = A[N][K](bf16) * Bt[M][K](bf16)^T
// FUSE: 0 plain | 1 GLU a*sigmoid(b) | 2 relu(a)*relu(b)  (f-width = M/2)
// OUT:  0 f32 | 1 bf16.   RES: 0 none | 1 f32 resid | 2 bf16 resid.
// 8x8 block-patch swizzle (gridDim.y==32 assumed) when gridDim.x%8==0.
// ---------------------------------------------------------------------------
template <int BN, int FUSE, int OUT, int RES>
__device__ __forceinline__ void gemm_body(
    const unsigned short* __restrict__ A, const unsigned short* __restrict__ Bt,
    void* __restrict__ Cout, const void* __restrict__ resid, int K, int M) {
  constexpr int NI = BN / 32;
  __shared__ __align__(16) unsigned short As[128 * 64];
  __shared__ __align__(16) unsigned short Bs[BN * 64];
  const int tid = threadIdx.x;
  const int wid = tid >> 6, lane = tid & 63;
  const int quad = lane >> 4, l16 = lane & 15;
  const int wm = (wid >> 1) * 64, wn = (wid & 1) * (BN / 2);

  int bx = blockIdx.x, by = blockIdx.y;
  if ((gridDim.x & 7) == 0) {           // 8x8 patch swizzle for L2 locality
    int pid = by * gridDim.x + bx;
    int inb = pid & 63, pidp = pid >> 6;
    by = (pidp & 3) * 8 + (inb & 7);
    bx = (pidp >> 2) * 8 + (inb >> 3);
  }
  const int row0 = by * 128;
  const int col0 = bx * BN;

  floatx4 acc[4][NI];
#pragma unroll
  for (int mi = 0; mi < 4; mi++)
#pragma unroll
    for (int ni = 0; ni < NI; ni++) acc[mi][ni] = (floatx4){0.f, 0.f, 0.f, 0.f};

  const unsigned short* Ag = A + (size_t)row0 * K;
  const unsigned short* Bg = Bt + (size_t)col0 * K;

  for (int k0 = 0; k0 < K; k0 += 64) {
#pragma unroll
    for (int j = 0; j < 4; j++) {
      int ci = tid + j * 256;
      int r = ci >> 3, c = (ci & 7) ^ (r & 7);
      glds16(Ag + (size_t)r * K + k0 + c * 8, &As[(wid * 64 + j * 256) * 8]);
    }
#pragma unroll
    for (int j = 0; j < BN / 32; j++) {
      int ci = tid + j * 256;
      int r = ci >> 3, c = (ci & 7) ^ (r & 7);
      glds16(Bg + (size_t)r * K + k0 + c * 8, &Bs[(wid * 64 + j * 256) * 8]);
    }
    __syncthreads();
#pragma unroll
    for (int kk = 0; kk < 64; kk += 32) {
      short8 a[4], b[NI];
#pragma unroll
      for (int mi = 0; mi < 4; mi++) {
        int r = wm + mi * 16 + l16;
        a[mi] = *(const short8*)&As[r * 64 + (((kk >> 3) + quad) ^ (r & 7)) * 8];
      }
#pragma unroll
      for (int ni = 0; ni < NI; ni++) {
        int r = wn + ni * 16 + l16;
        b[ni] = *(const short8*)&Bs[r * 64 + (((kk >> 3) + quad) ^ (r & 7)) * 8];
      }
#pragma unroll
      for (int mi = 0; mi < 4; mi++)
#pragma unroll
        for (int ni = 0; ni < NI; ni++)
          acc[mi][ni] = __builtin_amdgcn_mfma_f32_16x16x32_bf16(a[mi], b[ni], acc[mi][ni], 0, 0, 0);
    }
    __syncthreads();
  }

  if (FUSE == 0) {
#pragma unroll
    for (int mi = 0; mi < 4; mi++) {
#pragma unroll
      for (int reg = 0; reg < 4; reg++) {
        int grow = row0 + wm + mi * 16 + quad * 4 + reg;
#pragma unroll
        for (int ni = 0; ni < NI; ni++) {
          int gcol = col0 + wn + ni * 16 + l16;
          float v = acc[mi][ni][reg];
          if (RES == 1) v += ((const float*)resid)[(size_t)grow * M + gcol];
          if (RES == 2) v += bf2f(((const unsigned short*)resid)[(size_t)grow * M + gcol]);
          if (OUT == 1) ((unsigned short*)Cout)[(size_t)grow * M + gcol] = f2bf(v);
          else          ((float*)Cout)[(size_t)grow * M + gcol] = v;
        }
      }
    }
  } else {
    const int group = (col0 + wn) >> 6;
    const int MW = M >> 1;
#pragma unroll
    for (int mi = 0; mi < 4; mi++) {
#pragma unroll
      for (int reg = 0; reg < 4; reg++) {
        int grow = row0 + wm + mi * 16 + quad * 4 + reg;
#pragma unroll
        for (int ni = 0; ni < NI / 2; ni++) {
          int f = group * 32 + ni * 16 + l16;
          float a = acc[mi][ni][reg], b = acc[mi][ni + NI / 2][reg];
          float v;
          if (FUSE == 1) v = a / (1.0f + __expf(-b));
          else           v = fmaxf(a, 0.f) * fmaxf(b, 0.f);
          ((unsigned short*)Cout)[(size_t)grow * MW + f] = f2bf(v);
        }
      }
    }
  }
}

// Named wrappers (distinct rocprof identities)
__global__ __launch_bounds__(256, 2) void gemm_qkv(
    const unsigned short* A, const unsigned short* Bt, void* C, const void* r, int K, int M) {
  gemm_body<128, 0, 1, 0>(A, Bt, C, r, K, M);
}
__global__ __launch_bounds__(256, 2) void gemm_oproj(
    const unsigned short* A, const unsigned short* Bt, void* C, const void* r, int K, int M) {
  gemm_body<64, 0, 1, 1>(A, Bt, C, r, K, M);
}
__global__ __launch_bounds__(256, 2) void gemm_glu(
    const unsigned short* A, const unsigned short* Bt, void* C, const void* r, int K, int M) {
  gemm_body<128, 1, 1, 0>(A, Bt, C, r, K, M);
}
__global__ __launch_bounds__(256, 2) void gemm_dn(
    const unsigned short* A, const unsigned short* Bt, void* C, const void* r, int K, int M) {
  gemm_body<64, 0, 1, 2>(A, Bt, C, r, K, M);
}
__global__ __launch_bounds__(256, 2) void gemm_gateup(
    const unsigned short* A, const unsigned short* Bt, void* C, const void* r, int K, int M) {
  gemm_body<128, 2, 1, 0>(A, Bt, C, r, K, M);
}
__global__ __launch_bounds__(256, 2) void gemm_ffdn(
    const unsigned short* A, const unsigned short* Bt, void* C, const void* r, int K, int M) {
  gemm_body<64, 0, 0, 2>(A, Bt, C, r, K, M);
}

// ---------------------------------------------------------------------------
// Per-head zcrms (HD=64) + RoPE for q,k (bf16 in).
// q gets *QSCALE = log2(e)/8 folded in (flash uses exp2).
// ---------------------------------------------------------------------------
#define QSCALE 0.180336880111f   // log2(e)/8

__global__ __launch_bounds__(256) void qknorm_rope_kernel(
    const unsigned short* __restrict__ qkv, const float* __restrict__ cosb,
    const float* __restrict__ sinb, const float* __restrict__ qns,
    const float* __restrict__ kns, unsigned short* __restrict__ qb,
    unsigned short* __restrict__ kb) {
  int tok = blockIdx.x;
  int tid = threadIdx.x, w = tid >> 6, lane = tid & 63;
  int pos = tok & (TT - 1);
  int half = lane & 31;
  float c = cosb[pos * 32 + half], s = sinb[pos * 32 + half];
  const unsigned short* row = qkv + (size_t)tok * 1536;
  for (int hr = w; hr < 20; hr += 4) {   // 16 q-heads + 4 k-heads
    float v = bf2f(row[hr * 64 + lane]);
    float ss = v * v;
#pragma unroll
    for (int off = 32; off > 0; off >>= 1) ss += __shfl_xor(ss, off);
    float rinv = rsqrtf(ss * (1.0f / 64.0f) + 1e-6f);
    float sc = (hr < 16) ? qns[lane] : kns[lane];
    float nv = (1.0f + sc) * v * rinv;
    float partner = __shfl_xor(nv, 32);
    float outv = (lane < 32) ? (nv * c - partner * s) : (nv * c + partner * s);
    if (hr < 16) qb[(size_t)tok * 1024 + hr * 64 + lane] = f2bf(outv * QSCALE);
    else         kb[(size_t)tok * 256 + (hr - 16) * 64 + lane] = f2bf(outv);
  }
}

// ---------------------------------------------------------------------------
// V transpose straight from qkv GEMM output (bf16, offset 1280 in 1536 row):
// -> vt [(bi*4+kvh)*64+d][2048 keys]
// ---------------------------------------------------------------------------
__global__ __launch_bounds__(256) void vtrans_kernel(
    const unsigned short* __restrict__ qkv, unsigned short* __restrict__ vt) {
  __shared__ unsigned short t[64 * 65];
  int ktile = blockIdx.x;            // 0..31
  int g = blockIdx.y;                // bi*4+kvh, 0..7
  int bi = g >> 2, kvh = g & 3;
  int tid = threadIdx.x;
#pragma unroll
  for (int j = 0; j < 2; j++) {
    int ci = tid + j * 256;
    int r = ci >> 3, c8 = (ci & 7) * 8;
    union { uint4 v; unsigned short u[8]; } uu;
    uu.v = *(const uint4*)(qkv + (size_t)(bi * TT + ktile * 64 + r) * 1536 +
                           1280 + kvh * 64 + c8);
#pragma unroll
    for (int e = 0; e < 8; e++) t[r * 65 + c8 + e] = uu.u[e];
  }
  __syncthreads();
#pragma unroll
  for (int j = 0; j < 2; j++) {
    int ci = tid + j * 256;
    int d = ci >> 3, c8 = (ci & 7) * 8;
    union { uint4 v; unsigned short u[8]; } uu;
#pragma unroll
    for (int e = 0; e < 8; e++) uu.u[e] = t[(c8 + e) * 65 + d];
    *(uint4*)(vt + ((size_t)(g * 64 + d)) * TT + ktile * 64 + c8) = uu.v;
  }
}

// ---------------------------------------------------------------------------
// Flash attention.  256 q-rows/block, 8 waves x 32 q-rows, 512 threads,
// grid 8x32 = 256 blocks.  Q in regs; K,V^T staged via glds16 (XOR swizzle);
// one barrier/iter (double buffer).  S^T = K·Q^T so each lane holds 4
// CONSECUTIVE keys for one q-row -> P written as packed ds_write_b64 into
// Ps[qrow][key] (row-XOR chunk swizzle); pa read back as b128 A-frags.
// Rowsum via MFMA with ones.  LDS = 16K+16K+32K = 64 KB.
// ---------------------------------------------------------------------------
__global__ __launch_bounds__(512) void flash_kernel(
    const unsigned short* __restrict__ qb, const unsigned short* __restrict__ kb,
    const unsigned short* __restrict__ vt, unsigned short* __restrict__ ob) {
  const int qt = blockIdx.x;          // 0..7 (256 q rows)
  const int bh = blockIdx.y;          // 0..31
  const int bi = bh >> 4, h = bh & 15, kvh = h >> 2;
  const int tid = threadIdx.x, w = tid >> 6, lane = tid & 63;
  const int quad = lane >> 4, l16 = lane & 15;

  __shared__ __align__(16) unsigned short Ks[2][64 * 64];
  __shared__ __align__(16) unsigned short Vs[2][64 * 64];
  __shared__ __align__(16) unsigned short Ps[256 * 64];

  const unsigned short* qsrc = qb + ((size_t)(bi * TT + qt * 256)) * 1024 + h * 64;
  short8 qf[2][2];
#pragma unroll
  for (int af = 0; af < 2; af++) {
    const unsigned short* qr = qsrc + (size_t)(w * 32 + af * 16 + l16) * 1024;
    qf[af][0] = *(const short8*)(qr + quad * 8);
    qf[af][1] = *(const short8*)(qr + 32 + quad * 8);
  }

  const unsigned short* kbase = kb + ((size_t)(bi * TT)) * 256 + kvh * 64;
  const unsigned short* vbase = vt + ((size_t)(bi * 4 + kvh)) * (64 * TT);

  floatx4 oacc[2][4];
  floatx4 lacc[2];
#pragma unroll
  for (int af = 0; af < 2; af++) {
    lacc[af] = (floatx4){0.f, 0.f, 0.f, 0.f};
#pragma unroll
    for (int di = 0; di < 4; di++) oacc[af][di] = (floatx4){0.f, 0.f, 0.f, 0.f};
  }
  const short8 ones = (short8){0x3F80, 0x3F80, 0x3F80, 0x3F80,
                               0x3F80, 0x3F80, 0x3F80, 0x3F80};

  {  // prologue: stage kt=0 (512 chunks per tile, 1 per thread)
    int r = tid >> 3, c = (tid & 7) ^ (r & 7);
    glds16(kbase + (size_t)r * 256 + c * 8, &Ks[0][w * 512]);
    glds16(vbase + (size_t)r * TT + c * 8, &Vs[0][w * 512]);
  }

  for (int kt = 0; kt < 32; kt++) {
    const int buf = kt & 1;
    __syncthreads();
    if (kt < 31) {
      int r = tid >> 3, c = (tid & 7) ^ (r & 7);
      glds16(kbase + (size_t)((kt + 1) * 64 + r) * 256 + c * 8, &Ks[buf ^ 1][w * 512]);
      glds16(vbase + (size_t)r * TT + (kt + 1) * 64 + c * 8, &Vs[buf ^ 1][w * 512]);
    }

    short8 kf[4][2];
#pragma unroll
    for (int ni = 0; ni < 4; ni++) {
      int rb = ni * 16 + l16;
      kf[ni][0] = *(const short8*)&Ks[buf][rb * 64 + ((quad ^ (rb & 7)) * 8)];
      kf[ni][1] = *(const short8*)&Ks[buf][rb * 64 + (((4 + quad) ^ (rb & 7)) * 8)];
    }
    // ---- S^T = K·Q^T: lane holds keys ni*16+quad*4+{0..3} for qrow af*16+l16
#pragma unroll
    for (int af = 0; af < 2; af++) {
      const int rr = w * 32 + af * 16 + l16;
#pragma unroll
      for (int ni = 0; ni < 4; ni++) {
        floatx4 s = (floatx4){0.f, 0.f, 0.f, 0.f};
        s = __builtin_amdgcn_mfma_f32_16x16x32_bf16(kf[ni][0], qf[af][0], s, 0, 0, 0);
        s = __builtin_amdgcn_mfma_f32_16x16x32_bf16(kf[ni][1], qf[af][1], s, 0, 0, 0);
        union { unsigned short u[4]; unsigned long long ull; } pk;
#pragma unroll
        for (int r = 0; r < 4; r++)
          pk.u[r] = (unsigned short)(__float_as_uint(__builtin_amdgcn_exp2f(s[r])) >> 16);
        int ch = (ni * 2 + (quad >> 1)) ^ (rr & 7);
        *(unsigned long long*)&Ps[rr * 64 + ch * 8 + (quad & 1) * 4] = pk.ull;
      }
    }
    short8 vf[4][2];
#pragma unroll
    for (int di = 0; di < 4; di++) {
      int rb = di * 16 + l16;
      vf[di][0] = *(const short8*)&Vs[buf][rb * 64 + ((quad ^ (rb & 7)) * 8)];
      vf[di][1] = *(const short8*)&Vs[buf][rb * 64 + (((4 + quad) ^ (rb & 7)) * 8)];
    }
#pragma unroll
    for (int af = 0; af < 2; af++) {
      const int rr = w * 32 + af * 16 + l16;   // rr&7 == l16&7
      short8 pa0 = *(const short8*)&Ps[rr * 64 + ((quad ^ (rr & 7)) * 8)];
      short8 pa1 = *(const short8*)&Ps[rr * 64 + (((4 + quad) ^ (rr & 7)) * 8)];
      lacc[af] = __builtin_amdgcn_mfma_f32_16x16x32_bf16(pa0, ones, lacc[af], 0, 0, 0);
      lacc[af] = __builtin_amdgcn_mfma_f32_16x16x32_bf16(pa1, ones, lacc[af], 0, 0, 0);
#pragma unroll
      for (int di = 0; di < 4; di++) {
        oacc[af][di] = __builtin_amdgcn_mfma_f32_16x16x32_bf16(pa0, vf[di][0], oacc[af][di], 0, 0, 0);
        oacc[af][di] = __builtin_amdgcn_mfma_f32_16x16x32_bf16(pa1, vf[di][1], oacc[af][di], 0, 0, 0);
      }
    }
  }

  unsigned short* obase = ob + ((size_t)(bi * TT + qt * 256)) * 1024 + h * 64;
#pragma unroll
  for (int af = 0; af < 2; af++) {
    float rl[4];
#pragma unroll
    for (int r = 0; r < 4; r++) rl[r] = 1.0f / lacc[af][r];
#pragma unroll
    for (int di = 0; di < 4; di++)
#pragma unroll
      for (int r = 0; r < 4; r++) {
        int qrow = w * 32 + af * 16 + quad * 4 + r;
        obase[(size_t)qrow * 1024 + di * 16 + l16] = f2bf(oacc[af][di][r] * rl[r]);
      }
  }
}

// ---------------------------------------------------------------------------
// Depthwise conv (KW=15, SAME, per-batch time axis) + zcrms.  Block per token.
// ---------------------------------------------------------------------------
__global__ __launch_bounds__(256) void convnorm_kernel(
    const unsigned short* __restrict__ g, const float* __restrict__ dw,
    const float* __restrict__ scale, unsigned short* __restrict__ out) {
  int tok = blockIdx.x;
  int bi = tok >> 11, pos = tok & (TT - 1);
  int tid = threadIdx.x, c0 = tid * 4;
  float a0 = 0.f, a1 = 0.f, a2 = 0.f, a3 = 0.f;
#pragma unroll
  for (int wk = 0; wk < 15; wk++) {
    int pp = pos + wk - 7;
    if (pp < 0 || pp >= TT) continue;
    ushort4 gv = *(const ushort4*)(g + ((size_t)(bi * TT + pp)) * 1024 + c0);
    float4 kv = *(const float4*)(dw + wk * 1024 + c0);
    a0 += bf2f(gv.x) * kv.x;
    a1 += bf2f(gv.y) * kv.y;
    a2 += bf2f(gv.z) * kv.z;
    a3 += bf2f(gv.w) * kv.w;
  }
  float ss = a0 * a0 + a1 * a1 + a2 * a2 + a3 * a3;
#pragma unroll
  for (int off = 32; off > 0; off >>= 1) ss += __shfl_down(ss, off);
  __shared__ float red[4];
  if ((tid & 63) == 0) red[tid >> 6] = ss;
  __syncthreads();
  float rinv = rsqrtf((red[0] + red[1] + red[2] + red[3]) * (1.0f / 1024.0f) + 1e-6f);
  float4 sv = *(const float4*)(scale + c0);
  ushort4 o;
  o.x = f2bf((1.0f + sv.x) * a0 * rinv);
  o.y = f2bf((1.0f + sv.y) * a1 * rinv);
  o.z = f2bf((1.0f + sv.z) * a2 * rinv);
  o.w = f2bf((1.0f + sv.w) * a3 * rinv);
  *(ushort4*)(out + (size_t)tok * 1024 + c0) = o;
}

// ---------------------------------------------------------------------------
extern "C" void kernel_launch(void* const* d_in, const int* in_sizes, int n_in,
                              void* d_out, int out_size, void* d_ws, size_t ws_size,
                              hipStream_t stream) {
  const float* x        = (const float*)d_in[0];
  const float* cosb     = (const float*)d_in[2];
  const float* sinb     = (const float*)d_in[3];
  const float* attn_ns  = (const float*)d_in[4];
  const float* qkern    = (const float*)d_in[5];
  const float* kkern    = (const float*)d_in[6];
  const float* vkern    = (const float*)d_in[7];
  const float* qns      = (const float*)d_in[8];
  const float* kns      = (const float*)d_in[9];
  const float* okern    = (const float*)d_in[10];
  const float* conv_ns  = (const float*)d_in[11];
  const float* pwupk    = (const float*)d_in[12];
  const float* dwk      = (const float*)d_in[13];
  const float* convi_ns = (const float*)d_in[14];
  const float* pwdnk    = (const float*)d_in[15];
  const float* ffn_ns   = (const float*)d_in[16];
  const float* gatek    = (const float*)d_in[17];
  const float* upk      = (const float*)d_in[18];
  const float* downk    = (const float*)d_in[19];
  float* out = (float*)d_out;
  char* ws = (char*)d_ws;

  const size_t O_QKVT = 0;
  const size_t O_OT   = O_QKVT + (size_t)1536 * 1024 * 2;
  const size_t O_UPT  = O_OT   + (size_t)1024 * 1024 * 2;
  const size_t O_DNT  = O_UPT  + (size_t)2048 * 1024 * 2;
  const size_t O_GUT  = O_DNT  + (size_t)1024 * 1024 * 2;
  const size_t O_DWNT = O_GUT  + (size_t)8192 * 1024 * 2;
  const size_t O_H    = O_DWNT + (size_t)4096 * 1024 * 2;
  const size_t O_BIG1 = O_H    + (size_t)4096 * 1024 * 2;   // qkv bf16 / ff bf16
  const size_t O_QB   = O_BIG1 + (size_t)4096 * 8192 * 2;
  const size_t O_KB   = O_QB   + (size_t)4096 * 1024 * 2;
  const size_t O_VT   = O_KB   + (size_t)4096 * 256 * 2;
  const size_t O_ECN  = O_VT   + (size_t)8 * 64 * 2048 * 2; // attn bf16 / cn bf16
  const size_t O_X1   = O_ECN  + (size_t)4096 * 1024 * 2;   // bf16
  const size_t O_X2   = O_X1   + (size_t)4096 * 1024 * 2;   // bf16
  const size_t O_BIG2 = O_X2   + (size_t)4096 * 1024 * 2;   // g bf16

  unsigned short* qkvT = (unsigned short*)(ws + O_QKVT);
  unsigned short* oT   = (unsigned short*)(ws + O_OT);
  unsigned short* upT  = (unsigned short*)(ws + O_UPT);
  unsigned short* dnT  = (unsigned short*)(ws + O_DNT);
  unsigned short* guT  = (unsigned short*)(ws + O_GUT);
  unsigned short* dwT  = (unsigned short*)(ws + O_DWNT);
  unsigned short* hbuf = (unsigned short*)(ws + O_H);
  unsigned short* big1u = (unsigned short*)(ws + O_BIG1);
  unsigned short* qbuf = (unsigned short*)(ws + O_QB);
  unsigned short* kbuf = (unsigned short*)(ws + O_KB);
  unsigned short* vtb  = (unsigned short*)(ws + O_VT);
  unsigned short* ecn  = (unsigned short*)(ws + O_ECN);
  unsigned short* x1b  = (unsigned short*)(ws + O_X1);
  unsigned short* x2b  = (unsigned short*)(ws + O_X2);
  unsigned short* big2 = (unsigned short*)(ws + O_BIG2);

  WJobs tab;
  tab.src[0] = qkern;  tab.dst[0] = qkvT;                       tab.K[0] = 1024; tab.M[0] = 1024; tab.pm[0] = 0;
  tab.src[1] = kkern;  tab.dst[1] = qkvT + (size_t)1024 * 1024; tab.K[1] = 1024; tab.M[1] = 256;  tab.pm[1] = 0;
  tab.src[2] = vkern;  tab.dst[2] = qkvT + (size_t)1280 * 1024; tab.K[2] = 1024; tab.M[2] = 256;  tab.pm[2] = 0;
  tab.src[3] = okern;  tab.dst[3] = oT;                         tab.K[3] = 1024; tab.M[3] = 1024; tab.pm[3] = 0;
  tab.src[4] = pwupk;  tab.dst[4] = upT;                        tab.K[4] = 1024; tab.M[4] = 2048; tab.pm[4] = 1;
  tab.src[5] = pwdnk;  tab.dst[5] = dnT;                        tab.K[5] = 1024; tab.M[5] = 1024; tab.pm[5] = 0;
  tab.src[6] = gatek;  tab.dst[6] = guT;                        tab.K[6] = 1024; tab.M[6] = 4096; tab.pm[6] = 2;
  tab.src[7] = upk;    tab.dst[7] = guT;                        tab.K[7] = 1024; tab.M[7] = 4096; tab.pm[7] = 3;
  tab.src[8] = downk;  tab.dst[8] = dwT;                        tab.K[8] = 4096; tab.M[8] = 1024; tab.pm[8] = 0;
  tab.start[0] = 0;
  for (int i = 0; i < 9; i++)
    tab.start[i + 1] = tab.start[i] + (tab.M[i] >> 5) * (tab.K[i] >> 5);
  wconv_all_kernel<<<tab.start[9], 256, 0, stream>>>(tab);

  // attention block
  rmsnorm_kernel<false><<<NTOK, 256, 0, stream>>>(x, attn_ns, hbuf);
  gemm_qkv<<<dim3(12, 32), 256, 0, stream>>>(hbuf, qkvT, big1u, nullptr, 1024, 1536);
  qknorm_rope_kernel<<<NTOK, 256, 0, stream>>>(big1u, cosb, sinb, qns, kns,
                                               qbuf, kbuf);
  vtrans_kernel<<<dim3(32, 8), 256, 0, stream>>>(big1u, vtb);
  flash_kernel<<<dim3(8, 32), 512, 0, stream>>>(qbuf, kbuf, vtb, ecn);
  gemm_oproj<<<dim3(16, 32), 256, 0, stream>>>(ecn, oT, x1b, x, 1024, 1024);

  // conv block
  rmsnorm_kernel<true><<<NTOK, 256, 0, stream>>>(x1b, conv_ns, hbuf);
  gemm_glu<<<dim3(16, 32), 256, 0, stream>>>(hbuf, upT, big2, nullptr, 1024, 2048);
  convnorm_kernel<<<NTOK, 256, 0, stream>>>(big2, dwk, convi_ns, ecn);
  gemm_dn<<<dim3(16, 32), 256, 0, stream>>>(ecn, dnT, x2b, x1b, 1024, 1024);

  // ffn block
  rmsnorm_kernel<true><<<NTOK, 256, 0, stream>>>(x2b, ffn_ns, hbuf);
  gemm_gateup<<<dim3(64, 32), 256, 0, stream>>>(hbuf, guT, big1u, nullptr, 1024, 8192);
  gemm_ffdn<<<dim3(16, 32), 256, 0, stream>>>(big1u, dwT, out, x2b, 4096, 1024);
}

// Round 7
// 457.626 us; speedup vs baseline: 1.0677x; 1.0593x over previous
//
#include <hip/hip_runtime.h>

// ---------------------------------------------------------------------------
// EncoderBlock on MI355X (gfx950).  B=2 T=2048 D=1024 H=16 KVH=4 HD=64
// DFF=4096 KW=15.  bf16 MFMA GEMMs (16x16x32), fp32 accumulate.
// R7: qknorm+RoPE+V-transpose fused into qkv-GEMM epilogue (fp32-accurate,
// kills 2 kernels + 30MB traffic); L2 patch swizzle only for gridx==16.
// ---------------------------------------------------------------------------

#define TT   2048
#define NTOK 4096   // B*T

typedef __attribute__((ext_vector_type(8))) short short8;   // 8 x bf16
typedef __attribute__((ext_vector_type(4))) float floatx4;  // MFMA acc

__device__ __forceinline__ unsigned short f2bf(float f) {
  unsigned int u = __float_as_uint(f);
  u = (u + 0x7fffu + ((u >> 16) & 1u)) >> 16;   // RNE
  return (unsigned short)u;
}
__device__ __forceinline__ float bf2f(unsigned short s) {
  return __uint_as_float(((unsigned int)s) << 16);
}

// async global->LDS 16B DMA: LDS dst = wave-uniform base + lane*16
__device__ __forceinline__ void glds16(const void* g, void* lds_base) {
  __builtin_amdgcn_global_load_lds(
      (const __attribute__((address_space(1))) void*)g,
      (__attribute__((address_space(3))) void*)lds_base, 16, 0, 0);
}

// ---------------------------------------------------------------------------
// All 9 weight transposes fp32 [K][M] -> bf16 [M][K] in ONE launch.
// pm: 0 row=m | 1 pw_up pairing | 2 gate half | 3 up half
// ---------------------------------------------------------------------------
struct WJobs {
  const float* src[9];
  unsigned short* dst[9];
  int K[9], M[9], pm[9];
  int start[10];
};

__global__ __launch_bounds__(256) void wconv_all_kernel(WJobs tab) {
  int b = blockIdx.x;
  int j = 0;
  while (b >= tab.start[j + 1]) j++;
  int t = b - tab.start[j];
  const float* src = tab.src[j];
  unsigned short* dst = tab.dst[j];
  int K = tab.K[j], M = tab.M[j], pm = tab.pm[j];
  int mt = M >> 5;
  int m0 = (t % mt) * 32, k0 = (t / mt) * 32;
  int rowbase;
  if (pm == 0)      rowbase = m0;
  else if (pm == 1) rowbase = ((m0 & 1023) >> 5) * 64 + (m0 >> 10) * 32;
  else if (pm == 2) rowbase = (m0 >> 5) * 64;
  else              rowbase = (m0 >> 5) * 64 + 32;
  __shared__ float tile[32][33];
  int tx = threadIdx.x & 31, ty = threadIdx.x >> 5;  // 32 x 8
  for (int r = ty; r < 32; r += 8)
    tile[r][tx] = src[(size_t)(k0 + r) * M + m0 + tx];
  __syncthreads();
  for (int r = ty; r < 32; r += 8)
    dst[(size_t)(rowbase + r) * K + k0 + tx] = f2bf(tile[tx][r]);
}

// ---------------------------------------------------------------------------
// zcrms over D=1024: out_bf16 = (1+scale)*x/rms.  One block per token.
// ---------------------------------------------------------------------------
template <bool BF16IN>
__global__ __launch_bounds__(256) void rmsnorm_kernel(
    const void* __restrict__ xin, const float* __restrict__ scale,
    unsigned short* __restrict__ out) {
  int t = blockIdx.x, tid = threadIdx.x;
  float xv[4];
  if (BF16IN) {
    ushort4 u = ((const ushort4*)((const unsigned short*)xin + (size_t)t * 1024))[tid];
    xv[0] = bf2f(u.x); xv[1] = bf2f(u.y); xv[2] = bf2f(u.z); xv[3] = bf2f(u.w);
  } else {
    float4 u = ((const float4*)((const float*)xin + (size_t)t * 1024))[tid];
    xv[0] = u.x; xv[1] = u.y; xv[2] = u.z; xv[3] = u.w;
  }
  float ss = xv[0] * xv[0] + xv[1] * xv[1] + xv[2] * xv[2] + xv[3] * xv[3];
#pragma unroll
  for (int off = 32; off > 0; off >>= 1) ss += __shfl_down(ss, off);
  __shared__ float red[4];
  if ((tid & 63) == 0) red[tid >> 6] = ss;
  __syncthreads();
  float rinv = rsqrtf((red[0] + red[1] + red[2] + red[3]) * (1.0f / 1024.0f) + 1e-6f);
  float4 sv = ((const float4*)scale)[tid];
  ushort4 o;
  o.x = f2bf((1.0f + sv.x) * xv[0] * rinv);
  o.y = f2bf((1.0f + sv.y) * xv[1] * rinv);
  o.z = f2bf((1.0f + sv.z) * xv[2] * rinv);
  o.w = f2bf((1.0f + sv.w) * xv[3] * rinv);
  ((ushort4*)(out + (size_t)t * 1024))[tid] = o;
}

// ---------------------------------------------------------------------------
// GEMM body.  C[N][M] = A[N][K](bf16) * Bt[M][K](bf16)^T
// FUSE: 0 plain | 1 GLU a*sigmoid(b) | 2 relu(a)*relu(b)  (f-width = M/2)
// OUT:  0 f32 | 1 bf16.   RES: 0 none | 1 f32 resid | 2 bf16 resid.
// 8x8 patch swizzle only when gridDim.x==16 (R6: helps 16-wide, hurts 64).
// ---------------------------------------------------------------------------
template <int BN, int FUSE, int OUT, int RES>
__device__ __forceinline__ void gemm_body(
    const unsigned short* __restrict__ A, const unsigned short* __restrict__ Bt,
    void* __restrict__ Cout, const void* __restrict__ resid, int K, int M) {
  constexpr int NI = BN / 32;
  __shared__ __align__(16) unsigned short As[128 * 64];
  __shared__ __align__(16) unsigned short Bs[BN * 64];
  const int tid = threadIdx.x;
  const int wid = tid >> 6, lane = tid & 63;
  const int quad = lane >> 4, l16 = lane & 15;
  const int wm = (wid >> 1) * 64, wn = (wid & 1) * (BN / 2);

  int bx = blockIdx.x, by = blockIdx.y;
  if (gridDim.x == 16) {                // 8x8 patch swizzle for L2 locality
    int pid = by * gridDim.x + bx;
    int inb = pid & 63, pidp = pid >> 6;
    by = (pidp & 3) * 8 + (inb & 7);
    bx = (pidp >> 2) * 8 + (inb >> 3);
  }
  const int row0 = by * 128;
  const int col0 = bx * BN;

  floatx4 acc[4][NI];
#pragma unroll
  for (int mi = 0; mi < 4; mi++)
#pragma unroll
    for (int ni = 0; ni < NI; ni++) acc[mi][ni] = (floatx4){0.f, 0.f, 0.f, 0.f};

  const unsigned short* Ag = A + (size_t)row0 * K;
  const unsigned short* Bg = Bt + (size_t)col0 * K;

  for (int k0 = 0; k0 < K; k0 += 64) {
#pragma unroll
    for (int j = 0; j < 4; j++) {
      int ci = tid + j * 256;
      int r = ci >> 3, c = (ci & 7) ^ (r & 7);
      glds16(Ag + (size_t)r * K + k0 + c * 8, &As[(wid * 64 + j * 256) * 8]);
    }
#pragma unroll
    for (int j = 0; j < BN / 32; j++) {
      int ci = tid + j * 256;
      int r = ci >> 3, c = (ci & 7) ^ (r & 7);
      glds16(Bg + (size_t)r * K + k0 + c * 8, &Bs[(wid * 64 + j * 256) * 8]);
    }
    __syncthreads();
#pragma unroll
    for (int kk = 0; kk < 64; kk += 32) {
      short8 a[4], b[NI];
#pragma unroll
      for (int mi = 0; mi < 4; mi++) {
        int r = wm + mi * 16 + l16;
        a[mi] = *(const short8*)&As[r * 64 + (((kk >> 3) + quad) ^ (r & 7)) * 8];
      }
#pragma unroll
      for (int ni = 0; ni < NI; ni++) {
        int r = wn + ni * 16 + l16;
        b[ni] = *(const short8*)&Bs[r * 64 + (((kk >> 3) + quad) ^ (r & 7)) * 8];
      }
#pragma unroll
      for (int mi = 0; mi < 4; mi++)
#pragma unroll
        for (int ni = 0; ni < NI; ni++)
          acc[mi][ni] = __builtin_amdgcn_mfma_f32_16x16x32_bf16(a[mi], b[ni], acc[mi][ni], 0, 0, 0);
    }
    __syncthreads();
  }

  if (FUSE == 0) {
#pragma unroll
    for (int mi = 0; mi < 4; mi++) {
#pragma unroll
      for (int reg = 0; reg < 4; reg++) {
        int grow = row0 + wm + mi * 16 + quad * 4 + reg;
#pragma unroll
        for (int ni = 0; ni < NI; ni++) {
          int gcol = col0 + wn + ni * 16 + l16;
          float v = acc[mi][ni][reg];
          if (RES == 1) v += ((const float*)resid)[(size_t)grow * M + gcol];
          if (RES == 2) v += bf2f(((const unsigned short*)resid)[(size_t)grow * M + gcol]);
          if (OUT == 1) ((unsigned short*)Cout)[(size_t)grow * M + gcol] = f2bf(v);
          else          ((float*)Cout)[(size_t)grow * M + gcol] = v;
        }
      }
    }
  } else {
    const int group = (col0 + wn) >> 6;
    const int MW = M >> 1;
#pragma unroll
    for (int mi = 0; mi < 4; mi++) {
#pragma unroll
      for (int reg = 0; reg < 4; reg++) {
        int grow = row0 + wm + mi * 16 + quad * 4 + reg;
#pragma unroll
        for (int ni = 0; ni < NI / 2; ni++) {
          int f = group * 32 + ni * 16 + l16;
          float a = acc[mi][ni][reg], b = acc[mi][ni + NI / 2][reg];
          float v;
          if (FUSE == 1) v = a / (1.0f + __expf(-b));
          else           v = fmaxf(a, 0.f) * fmaxf(b, 0.f);
          ((unsigned short*)Cout)[(size_t)grow * MW + f] = f2bf(v);
        }
      }
    }
  }
}

// Named wrappers (distinct rocprof identities)
__global__ __launch_bounds__(256, 2) void gemm_oproj(
    const unsigned short* A, const unsigned short* Bt, void* C, const void* r, int K, int M) {
  gemm_body<64, 0, 1, 1>(A, Bt, C, r, K, M);
}
__global__ __launch_bounds__(256, 2) void gemm_glu(
    const unsigned short* A, const unsigned short* Bt, void* C, const void* r, int K, int M) {
  gemm_body<128, 1, 1, 0>(A, Bt, C, r, K, M);
}
__global__ __launch_bounds__(256, 2) void gemm_dn(
    const unsigned short* A, const unsigned short* Bt, void* C, const void* r, int K, int M) {
  gemm_body<64, 0, 1, 2>(A, Bt, C, r, K, M);
}
__global__ __launch_bounds__(256, 2) void gemm_gateup(
    const unsigned short* A, const unsigned short* Bt, void* C, const void* r, int K, int M) {
  gemm_body<128, 2, 1, 0>(A, Bt, C, r, K, M);
}
__global__ __launch_bounds__(256, 2) void gemm_ffdn(
    const unsigned short* A, const unsigned short* Bt, void* C, const void* r, int K, int M) {
  gemm_body<64, 0, 0, 2>(A, Bt, C, r, K, M);
}

// ---------------------------------------------------------------------------
// qkv GEMM with FUSED per-head zcrms + RoPE + V-transpose epilogue.
// A = hbuf [4096][1024] bf16, Bt = qkvT [1536][1024] bf16.
// Wave's 64-col slab == one head.  C-frag: lane holds rows quad*4+{0..3}
// (+mi*16), cols l16+{0,16,32,48} (ni).  Head-RMS = Σ_ni + shfl_xor(1,2,4,8).
// RoPE partner (c±32) = ni±2, same lane.  q *= QSCALE (=log2e/8, flash exp2).
// V: 4 consecutive keys per (mi,ni) -> packed 8B store into vt[d][key].
// ---------------------------------------------------------------------------
#define QSCALE 0.180336880111f   // log2(e)/8

__global__ __launch_bounds__(256, 2) void gemm_qkvf(
    const unsigned short* __restrict__ A, const unsigned short* __restrict__ Bt,
    const float* __restrict__ cosb, const float* __restrict__ sinb,
    const float* __restrict__ qns, const float* __restrict__ kns,
    unsigned short* __restrict__ qb, unsigned short* __restrict__ kb,
    unsigned short* __restrict__ vt) {
  constexpr int K = 1024;
  __shared__ __align__(16) unsigned short As[128 * 64];
  __shared__ __align__(16) unsigned short Bs[128 * 64];
  const int tid = threadIdx.x;
  const int wid = tid >> 6, lane = tid & 63;
  const int quad = lane >> 4, l16 = lane & 15;
  const int wm = (wid >> 1) * 64, wn = (wid & 1) * 64;
  const int row0 = blockIdx.y * 128;
  const int col0 = blockIdx.x * 128;

  floatx4 acc[4][4];
#pragma unroll
  for (int mi = 0; mi < 4; mi++)
#pragma unroll
    for (int ni = 0; ni < 4; ni++) acc[mi][ni] = (floatx4){0.f, 0.f, 0.f, 0.f};

  const unsigned short* Ag = A + (size_t)row0 * K;
  const unsigned short* Bg = Bt + (size_t)col0 * K;

  for (int k0 = 0; k0 < K; k0 += 64) {
#pragma unroll
    for (int j = 0; j < 4; j++) {
      int ci = tid + j * 256;
      int r = ci >> 3, c = (ci & 7) ^ (r & 7);
      glds16(Ag + (size_t)r * K + k0 + c * 8, &As[(wid * 64 + j * 256) * 8]);
      glds16(Bg + (size_t)r * K + k0 + c * 8, &Bs[(wid * 64 + j * 256) * 8]);
    }
    __syncthreads();
#pragma unroll
    for (int kk = 0; kk < 64; kk += 32) {
      short8 a[4], b[4];
#pragma unroll
      for (int mi = 0; mi < 4; mi++) {
        int r = wm + mi * 16 + l16;
        a[mi] = *(const short8*)&As[r * 64 + (((kk >> 3) + quad) ^ (r & 7)) * 8];
      }
#pragma unroll
      for (int ni = 0; ni < 4; ni++) {
        int r = wn + ni * 16 + l16;
        b[ni] = *(const short8*)&Bs[r * 64 + (((kk >> 3) + quad) ^ (r & 7)) * 8];
      }
#pragma unroll
      for (int mi = 0; mi < 4; mi++)
#pragma unroll
        for (int ni = 0; ni < 4; ni++)
          acc[mi][ni] = __builtin_amdgcn_mfma_f32_16x16x32_bf16(a[mi], b[ni], acc[mi][ni], 0, 0, 0);
    }
    __syncthreads();
  }

  const int head = (col0 + wn) >> 6;       // 0..23
  const int bi = row0 >> 11;

  if (head < 20) {                          // q (0..15) or k (16..19): norm+RoPE
    const float* ns = (head < 16) ? qns : kns;
    float sc[4];
#pragma unroll
    for (int ni = 0; ni < 4; ni++) sc[ni] = 1.0f + ns[ni * 16 + l16];
#pragma unroll
    for (int mi = 0; mi < 4; mi++) {
#pragma unroll
      for (int reg = 0; reg < 4; reg++) {
        int row = row0 + wm + mi * 16 + quad * 4 + reg;
        int pos = row & (TT - 1);
        float ss = acc[mi][0][reg] * acc[mi][0][reg] + acc[mi][1][reg] * acc[mi][1][reg] +
                   acc[mi][2][reg] * acc[mi][2][reg] + acc[mi][3][reg] * acc[mi][3][reg];
        ss += __shfl_xor(ss, 1); ss += __shfl_xor(ss, 2);
        ss += __shfl_xor(ss, 4); ss += __shfl_xor(ss, 8);
        float rinv = rsqrtf(ss * (1.0f / 64.0f) + 1e-6f);
        float c0 = cosb[pos * 32 + l16],      s0 = sinb[pos * 32 + l16];
        float c1 = cosb[pos * 32 + 16 + l16], s1 = sinb[pos * 32 + 16 + l16];
        float nv0 = sc[0] * acc[mi][0][reg] * rinv;
        float nv1 = sc[1] * acc[mi][1][reg] * rinv;
        float nv2 = sc[2] * acc[mi][2][reg] * rinv;
        float nv3 = sc[3] * acc[mi][3][reg] * rinv;
        float o0 = nv0 * c0 - nv2 * s0;
        float o1 = nv1 * c1 - nv3 * s1;
        float o2 = nv2 * c0 + nv0 * s0;
        float o3 = nv3 * c1 + nv1 * s1;
        if (head < 16) {
          unsigned short* d = qb + (size_t)row * 1024 + head * 64 + l16;
          d[0] = f2bf(o0 * QSCALE); d[16] = f2bf(o1 * QSCALE);
          d[32] = f2bf(o2 * QSCALE); d[48] = f2bf(o3 * QSCALE);
        } else {
          unsigned short* d = kb + (size_t)row * 256 + (head - 16) * 64 + l16;
          d[0] = f2bf(o0); d[16] = f2bf(o1); d[32] = f2bf(o2); d[48] = f2bf(o3);
        }
      }
    }
  } else {                                  // v: plain bf16, transposed store
    const int g = bi * 4 + (head - 20);
    const int key0 = (row0 & (TT - 1)) + wm + quad * 4;
#pragma unroll
    for (int mi = 0; mi < 4; mi++) {
#pragma unroll
      for (int ni = 0; ni < 4; ni++) {
        int d = ni * 16 + l16;
        ushort4 pk;
        pk.x = f2bf(acc[mi][ni][0]); pk.y = f2bf(acc[mi][ni][1]);
        pk.z = f2bf(acc[mi][ni][2]); pk.w = f2bf(acc[mi][ni][3]);
        *(ushort4*)(vt + ((size_t)(g * 64 + d)) * TT + key0 + mi * 16) = pk;
      }
    }
  }
}

// ---------------------------------------------------------------------------
// Flash attention.  256 q-rows/block, 8 waves x 32 q-rows, 512 threads,
// grid 8x32 = 256 blocks.  Q in regs; K,V^T staged via glds16 (XOR swizzle);
// one barrier/iter (double buffer).  S^T = K·Q^T -> packed ds_write_b64 P;
// pa read back as b128 A-frags.  Rowsum via MFMA with ones.  LDS = 64 KB.
// ---------------------------------------------------------------------------
__global__ __launch_bounds__(512) void flash_kernel(
    const unsigned short* __restrict__ qb, const unsigned short* __restrict__ kb,
    const unsigned short* __restrict__ vt, unsigned short* __restrict__ ob) {
  const int qt = blockIdx.x;          // 0..7 (256 q rows)
  const int bh = blockIdx.y;          // 0..31
  const int bi = bh >> 4, h = bh & 15, kvh = h >> 2;
  const int tid = threadIdx.x, w = tid >> 6, lane = tid & 63;
  const int quad = lane >> 4, l16 = lane & 15;

  __shared__ __align__(16) unsigned short Ks[2][64 * 64];
  __shared__ __align__(16) unsigned short Vs[2][64 * 64];
  __shared__ __align__(16) unsigned short Ps[256 * 64];

  const unsigned short* qsrc = qb + ((size_t)(bi * TT + qt * 256)) * 1024 + h * 64;
  short8 qf[2][2];
#pragma unroll
  for (int af = 0; af < 2; af++) {
    const unsigned short* qr = qsrc + (size_t)(w * 32 + af * 16 + l16) * 1024;
    qf[af][0] = *(const short8*)(qr + quad * 8);
    qf[af][1] = *(const short8*)(qr + 32 + quad * 8);
  }

  const unsigned short* kbase = kb + ((size_t)(bi * TT)) * 256 + kvh * 64;
  const unsigned short* vbase = vt + ((size_t)(bi * 4 + kvh)) * (64 * TT);

  floatx4 oacc[2][4];
  floatx4 lacc[2];
#pragma unroll
  for (int af = 0; af < 2; af++) {
    lacc[af] = (floatx4){0.f, 0.f, 0.f, 0.f};
#pragma unroll
    for (int di = 0; di < 4; di++) oacc[af][di] = (floatx4){0.f, 0.f, 0.f, 0.f};
  }
  const short8 ones = (short8){0x3F80, 0x3F80, 0x3F80, 0x3F80,
                               0x3F80, 0x3F80, 0x3F80, 0x3F80};

  {  // prologue: stage kt=0
    int r = tid >> 3, c = (tid & 7) ^ (r & 7);
    glds16(kbase + (size_t)r * 256 + c * 8, &Ks[0][w * 512]);
    glds16(vbase + (size_t)r * TT + c * 8, &Vs[0][w * 512]);
  }

  for (int kt = 0; kt < 32; kt++) {
    const int buf = kt & 1;
    __syncthreads();
    if (kt < 31) {
      int r = tid >> 3, c = (tid & 7) ^ (r & 7);
      glds16(kbase + (size_t)((kt + 1) * 64 + r) * 256 + c * 8, &Ks[buf ^ 1][w * 512]);
      glds16(vbase + (size_t)r * TT + (kt + 1) * 64 + c * 8, &Vs[buf ^ 1][w * 512]);
    }

    short8 kf[4][2];
#pragma unroll
    for (int ni = 0; ni < 4; ni++) {
      int rb = ni * 16 + l16;
      kf[ni][0] = *(const short8*)&Ks[buf][rb * 64 + ((quad ^ (rb & 7)) * 8)];
      kf[ni][1] = *(const short8*)&Ks[buf][rb * 64 + (((4 + quad) ^ (rb & 7)) * 8)];
    }
    // ---- S^T = K·Q^T: lane holds keys ni*16+quad*4+{0..3} for qrow af*16+l16
#pragma unroll
    for (int af = 0; af < 2; af++) {
      const int rr = w * 32 + af * 16 + l16;
#pragma unroll
      for (int ni = 0; ni < 4; ni++) {
        floatx4 s = (floatx4){0.f, 0.f, 0.f, 0.f};
        s = __builtin_amdgcn_mfma_f32_16x16x32_bf16(kf[ni][0], qf[af][0], s, 0, 0, 0);
        s = __builtin_amdgcn_mfma_f32_16x16x32_bf16(kf[ni][1], qf[af][1], s, 0, 0, 0);
        union { unsigned short u[4]; unsigned long long ull; } pk;
#pragma unroll
        for (int r = 0; r < 4; r++)
          pk.u[r] = (unsigned short)(__float_as_uint(__builtin_amdgcn_exp2f(s[r])) >> 16);
        int ch = (ni * 2 + (quad >> 1)) ^ (rr & 7);
        *(unsigned long long*)&Ps[rr * 64 + ch * 8 + (quad & 1) * 4] = pk.ull;
      }
    }
    short8 vf[4][2];
#pragma unroll
    for (int di = 0; di < 4; di++) {
      int rb = di * 16 + l16;
      vf[di][0] = *(const short8*)&Vs[buf][rb * 64 + ((quad ^ (rb & 7)) * 8)];
      vf[di][1] = *(const short8*)&Vs[buf][rb * 64 + (((4 + quad) ^ (rb & 7)) * 8)];
    }
#pragma unroll
    for (int af = 0; af < 2; af++) {
      const int rr = w * 32 + af * 16 + l16;   // rr&7 == l16&7
      short8 pa0 = *(const short8*)&Ps[rr * 64 + ((quad ^ (rr & 7)) * 8)];
      short8 pa1 = *(const short8*)&Ps[rr * 64 + (((4 + quad) ^ (rr & 7)) * 8)];
      lacc[af] = __builtin_amdgcn_mfma_f32_16x16x32_bf16(pa0, ones, lacc[af], 0, 0, 0);
      lacc[af] = __builtin_amdgcn_mfma_f32_16x16x32_bf16(pa1, ones, lacc[af], 0, 0, 0);
#pragma unroll
      for (int di = 0; di < 4; di++) {
        oacc[af][di] = __builtin_amdgcn_mfma_f32_16x16x32_bf16(pa0, vf[di][0], oacc[af][di], 0, 0, 0);
        oacc[af][di] = __builtin_amdgcn_mfma_f32_16x16x32_bf16(pa1, vf[di][1], oacc[af][di], 0, 0, 0);
      }
    }
  }

  unsigned short* obase = ob + ((size_t)(bi * TT + qt * 256)) * 1024 + h * 64;
#pragma unroll
  for (int af = 0; af < 2; af++) {
    float rl[4];
#pragma unroll
    for (int r = 0; r < 4; r++) rl[r] = 1.0f / lacc[af][r];
#pragma unroll
    for (int di = 0; di < 4; di++)
#pragma unroll
      for (int r = 0; r < 4; r++) {
        int qrow = w * 32 + af * 16 + quad * 4 + r;
        obase[(size_t)qrow * 1024 + di * 16 + l16] = f2bf(oacc[af][di][r] * rl[r]);
      }
  }
}

// ---------------------------------------------------------------------------
// Depthwise conv (KW=15, SAME, per-batch time axis) + zcrms.  Block per token.
// ---------------------------------------------------------------------------
__global__ __launch_bounds__(256) void convnorm_kernel(
    const unsigned short* __restrict__ g, const float* __restrict__ dw,
    const float* __restrict__ scale, unsigned short* __restrict__ out) {
  int tok = blockIdx.x;
  int bi = tok >> 11, pos = tok & (TT - 1);
  int tid = threadIdx.x, c0 = tid * 4;
  float a0 = 0.f, a1 = 0.f, a2 = 0.f, a3 = 0.f;
#pragma unroll
  for (int wk = 0; wk < 15; wk++) {
    int pp = pos + wk - 7;
    if (pp < 0 || pp >= TT) continue;
    ushort4 gv = *(const ushort4*)(g + ((size_t)(bi * TT + pp)) * 1024 + c0);
    float4 kv = *(const float4*)(dw + wk * 1024 + c0);
    a0 += bf2f(gv.x) * kv.x;
    a1 += bf2f(gv.y) * kv.y;
    a2 += bf2f(gv.z) * kv.z;
    a3 += bf2f(gv.w) * kv.w;
  }
  float ss = a0 * a0 + a1 * a1 + a2 * a2 + a3 * a3;
#pragma unroll
  for (int off = 32; off > 0; off >>= 1) ss += __shfl_down(ss, off);
  __shared__ float red[4];
  if ((tid & 63) == 0) red[tid >> 6] = ss;
  __syncthreads();
  float rinv = rsqrtf((red[0] + red[1] + red[2] + red[3]) * (1.0f / 1024.0f) + 1e-6f);
  float4 sv = *(const float4*)(scale + c0);
  ushort4 o;
  o.x = f2bf((1.0f + sv.x) * a0 * rinv);
  o.y = f2bf((1.0f + sv.y) * a1 * rinv);
  o.z = f2bf((1.0f + sv.z) * a2 * rinv);
  o.w = f2bf((1.0f + sv.w) * a3 * rinv);
  *(ushort4*)(out + (size_t)tok * 1024 + c0) = o;
}

// ---------------------------------------------------------------------------
extern "C" void kernel_launch(void* const* d_in, const int* in_sizes, int n_in,
                              void* d_out, int out_size, void* d_ws, size_t ws_size,
                              hipStream_t stream) {
  const float* x        = (const float*)d_in[0];
  const float* cosb     = (const float*)d_in[2];
  const float* sinb     = (const float*)d_in[3];
  const float* attn_ns  = (const float*)d_in[4];
  const float* qkern    = (const float*)d_in[5];
  const float* kkern    = (const float*)d_in[6];
  const float* vkern    = (const float*)d_in[7];
  const float* qns      = (const float*)d_in[8];
  const float* kns      = (const float*)d_in[9];
  const float* okern    = (const float*)d_in[10];
  const float* conv_ns  = (const float*)d_in[11];
  const float* pwupk    = (const float*)d_in[12];
  const float* dwk      = (const float*)d_in[13];
  const float* convi_ns = (const float*)d_in[14];
  const float* pwdnk    = (const float*)d_in[15];
  const float* ffn_ns   = (const float*)d_in[16];
  const float* gatek    = (const float*)d_in[17];
  const float* upk      = (const float*)d_in[18];
  const float* downk    = (const float*)d_in[19];
  float* out = (float*)d_out;
  char* ws = (char*)d_ws;

  const size_t O_QKVT = 0;
  const size_t O_OT   = O_QKVT + (size_t)1536 * 1024 * 2;
  const size_t O_UPT  = O_OT   + (size_t)1024 * 1024 * 2;
  const size_t O_DNT  = O_UPT  + (size_t)2048 * 1024 * 2;
  const size_t O_GUT  = O_DNT  + (size_t)1024 * 1024 * 2;
  const size_t O_DWNT = O_GUT  + (size_t)8192 * 1024 * 2;
  const size_t O_H    = O_DWNT + (size_t)4096 * 1024 * 2;
  const size_t O_BIG1 = O_H    + (size_t)4096 * 1024 * 2;   // ff bf16
  const size_t O_QB   = O_BIG1 + (size_t)4096 * 8192 * 2;
  const size_t O_KB   = O_QB   + (size_t)4096 * 1024 * 2;
  const size_t O_VT   = O_KB   + (size_t)4096 * 256 * 2;
  const size_t O_ECN  = O_VT   + (size_t)8 * 64 * 2048 * 2; // attn bf16 / cn bf16
  const size_t O_X1   = O_ECN  + (size_t)4096 * 1024 * 2;   // bf16
  const size_t O_X2   = O_X1   + (size_t)4096 * 1024 * 2;   // bf16
  const size_t O_BIG2 = O_X2   + (size_t)4096 * 1024 * 2;   // g bf16

  unsigned short* qkvT = (unsigned short*)(ws + O_QKVT);
  unsigned short* oT   = (unsigned short*)(ws + O_OT);
  unsigned short* upT  = (unsigned short*)(ws + O_UPT);
  unsigned short* dnT  = (unsigned short*)(ws + O_DNT);
  unsigned short* guT  = (unsigned short*)(ws + O_GUT);
  unsigned short* dwT  = (unsigned short*)(ws + O_DWNT);
  unsigned short* hbuf = (unsigned short*)(ws + O_H);
  unsigned short* big1u = (unsigned short*)(ws + O_BIG1);
  unsigned short* qbuf = (unsigned short*)(ws + O_QB);
  unsigned short* kbuf = (unsigned short*)(ws + O_KB);
  unsigned short* vtb  = (unsigned short*)(ws + O_VT);
  unsigned short* ecn  = (unsigned short*)(ws + O_ECN);
  unsigned short* x1b  = (unsigned short*)(ws + O_X1);
  unsigned short* x2b  = (unsigned short*)(ws + O_X2);
  unsigned short* big2 = (unsigned short*)(ws + O_BIG2);

  WJobs tab;
  tab.src[0] = qkern;  tab.dst[0] = qkvT;                       tab.K[0] = 1024; tab.M[0] = 1024; tab.pm[0] = 0;
  tab.src[1] = kkern;  tab.dst[1] = qkvT + (size_t)1024 * 1024; tab.K[1] = 1024; tab.M[1] = 256;  tab.pm[1] = 0;
  tab.src[2] = vkern;  tab.dst[2] = qkvT + (size_t)1280 * 1024; tab.K[2] = 1024; tab.M[2] = 256;  tab.pm[2] = 0;
  tab.src[3] = okern;  tab.dst[3] = oT;                         tab.K[3] = 1024; tab.M[3] = 1024; tab.pm[3] = 0;
  tab.src[4] = pwupk;  tab.dst[4] = upT;                        tab.K[4] = 1024; tab.M[4] = 2048; tab.pm[4] = 1;
  tab.src[5] = pwdnk;  tab.dst[5] = dnT;                        tab.K[5] = 1024; tab.M[5] = 1024; tab.pm[5] = 0;
  tab.src[6] = gatek;  tab.dst[6] = guT;                        tab.K[6] = 1024; tab.M[6] = 4096; tab.pm[6] = 2;
  tab.src[7] = upk;    tab.dst[7] = guT;                        tab.K[7] = 1024; tab.M[7] = 4096; tab.pm[7] = 3;
  tab.src[8] = downk;  tab.dst[8] = dwT;                        tab.K[8] = 4096; tab.M[8] = 1024; tab.pm[8] = 0;
  tab.start[0] = 0;
  for (int i = 0; i < 9; i++)
    tab.start[i + 1] = tab.start[i] + (tab.M[i] >> 5) * (tab.K[i] >> 5);
  wconv_all_kernel<<<tab.start[9], 256, 0, stream>>>(tab);

  // attention block
  rmsnorm_kernel<false><<<NTOK, 256, 0, stream>>>(x, attn_ns, hbuf);
  gemm_qkvf<<<dim3(12, 32), 256, 0, stream>>>(hbuf, qkvT, cosb, sinb, qns, kns,
                                              qbuf, kbuf, vtb);
  flash_kernel<<<dim3(8, 32), 512, 0, stream>>>(qbuf, kbuf, vtb, ecn);
  gemm_oproj<<<dim3(16, 32), 256, 0, stream>>>(ecn, oT, x1b, x, 1024, 1024);

  // conv block
  rmsnorm_kernel<true><<<NTOK, 256, 0, stream>>>(x1b, conv_ns, hbuf);
  gemm_glu<<<dim3(16, 32), 256, 0, stream>>>(hbuf, upT, big2, nullptr, 1024, 2048);
  convnorm_kernel<<<NTOK, 256, 0, stream>>>(big2, dwk, convi_ns, ecn);
  gemm_dn<<<dim3(16, 32), 256, 0, stream>>>(ecn, dnT, x2b, x1b, 1024, 1024);

  // ffn block
  rmsnorm_kernel<true><<<NTOK, 256, 0, stream>>>(x2b, ffn_ns, hbuf);
  gemm_gateup<<<dim3(64, 32), 256, 0, stream>>>(hbuf, guT, big1u, nullptr, 1024, 8192);
  gemm_ffdn<<<dim3(16, 32), 256, 0, stream>>>(big1u, dwT, out, x2b, 4096, 1024);
}